// Round 5
// baseline (703.969 us; speedup 1.0000x reference)
//
#include <hip/hip_runtime.h>

// ---------------------------------------------------------------------------
// EdgeFeatures (fp32 in / fp32 out):
//   out[i] = (e[i] @ Us_w^T + Us_b) + Vx[src[i]] + Vx[dst[i]]
//   Vx     = x @ Vs_w^T + Vs_b
// H=256, V=10000, E=300000.
// Round-5 structure: all-of-A-upfront burst + n-split=4 for 4 blocks/CU.
//  - Block = 128 rows x 64 cols. B quarter (64x256 bf16 = 32KB) staged once
//    via global_load_lds in FRAGMENT ORDER (ws pre-permuted; rule #21) ->
//    K-loop ds_read_b128 = group_base + lane*16, conflict-free.
//  - A: wave = 32 rows; full K-slice issued before the single barrier;
//    barrier vmcnt(0) drain IS the BW phase; 8-kstep MFMA burst stall-free.
//  - 32KB LDS + VGPR<=128 -> 4 blocks/CU (round-4: 64KB -> 2 blocks/CU was
//    the overlap limiter: HBM 3.7 TB/s, everything else idle).
//  - Bijective XCD-chunk swizzle (m204): the 4 n-quarter siblings of a
//    row-group are dispatch-adjacent on the SAME XCD -> e rows HBM-fetched
//    once, siblings hit XCD L2 (A would otherwise be read 4x).
//  - Epilogue: per-wave LDS transpose (aliases B LDS after one barrier) so
//    Vx gathers are bf16x4 and stores dwordx4 coalesced.
// ws layout: [0,128K) Us_w bf16 frag-order | [128K,256K) Vs_w | [256K,+5.12M) Vx
// ---------------------------------------------------------------------------

typedef __bf16 bf16_t;
typedef __bf16 bf16x4 __attribute__((ext_vector_type(4)));
typedef __bf16 bf16x8 __attribute__((ext_vector_type(8)));
typedef float f32x4 __attribute__((ext_vector_type(4)));
typedef float f32x8 __attribute__((ext_vector_type(8)));

#define HDIM 256
#define NV 10000
#define NE 300000

__device__ __forceinline__ void async16(const bf16_t* g, bf16_t* l) {
  __builtin_amdgcn_global_load_lds(
      (const __attribute__((address_space(1))) void*)g,
      (__attribute__((address_space(3))) void*)l, 16, 0, 0);
}

// fp32 -> bf16 convert + permute both 256x256 weights into fragment order,
// 4 n-quarters of 32KB each. Chunk c (16B = 8 bf16):
//   h = c>>11 (n-quarter), idx = c&2047, g2 = idx>>6 (= ks*4 + ni), ln = idx&63
//   n = h*64 + ni*16 + (ln&15), kb = ks*32 + (ln>>4)*8
// In-kernel read: quarter base + (ks*4+ni)*1024B + lane*16B.
__global__ __launch_bounds__(256) void cvt_weights(
    const float* __restrict__ us, const float* __restrict__ vs,
    bf16_t* __restrict__ us_o, bf16_t* __restrict__ vs_o) {
  const int c = blockIdx.x * 256 + threadIdx.x;  // 0..8191 (32 blocks)
  const int h = c >> 11;
  const int idx = c & 2047;
  const int g2 = idx >> 6;
  const int ln = idx & 63;
  const int ni = g2 & 3;
  const int ks = g2 >> 2;
  const int n = h * 64 + ni * 16 + (ln & 15);
  const int kb = ks * 32 + (ln >> 4) * 8;
  const float* su = us + n * HDIM + kb;
  const float* sv = vs + n * HDIM + kb;
  f32x4 a0 = *(const f32x4*)su, a1 = *(const f32x4*)(su + 4);
  f32x4 b0 = *(const f32x4*)sv, b1 = *(const f32x4*)(sv + 4);
  f32x8 av = {a0[0], a0[1], a0[2], a0[3], a1[0], a1[1], a1[2], a1[3]};
  f32x8 bv = {b0[0], b0[1], b0[2], b0[3], b1[0], b1[1], b1[2], b1[3]};
  *(bf16x8*)(us_o + c * 8) = __builtin_convertvector(av, bf16x8);
  *(bf16x8*)(vs_o + c * 8) = __builtin_convertvector(bv, bf16x8);
}

template <bool FUSED>
__global__ __launch_bounds__(256, 4) void gemm(
    const float* __restrict__ A,      // M x 256 fp32 (e or x)
    const bf16_t* __restrict__ Wb,    // frag-order 4x16384 bf16 (4 n-quarters)
    const float* __restrict__ bias,   // 256 fp32
    const int* __restrict__ sIdxG,    // FUSED: src indices (E)
    const int* __restrict__ dIdxG,    // FUSED: dst indices (E)
    const bf16_t* __restrict__ Vx,    // FUSED: V x 256 bf16
    float* __restrict__ outF,         // FUSED: M x 256 fp32
    bf16_t* __restrict__ outB,        // !FUSED: M x 256 bf16 (Vx scratch)
    int M) {
  // LDS: [0,32K) B quarter (frag order). Epilogue staging aliases [0,17408).
  __shared__ __align__(16) char smem[32768];

  const int tid = threadIdx.x;  // 0..255
  const int lane = tid & 63;
  const int wave = tid >> 6;   // 0..3: wave owns rows [wave*32, wave*32+32)
  const int l15 = lane & 15;
  const int quad = lane >> 4;  // 0..3

  // --- bijective XCD-chunk swizzle (m204): hw maps bid%8 -> XCD; give each
  // XCD a contiguous chunk of lin, so the 4 n-quarter siblings of a row-
  // group (lin = rg*4 + nq) run dispatch-adjacent on the SAME XCD.
  const int Nb = gridDim.x;
  const int q = Nb >> 3, r = Nb & 7;
  const int xcd = blockIdx.x & 7, bidx = blockIdx.x >> 3;
  const int lin = (xcd < r) ? (xcd * (q + 1) + bidx)
                            : (r * (q + 1) + (xcd - r) * q + bidx);
  const int n0 = (lin & 3) * 64;
  const int row0 = (lin >> 2) * 128;

  // --- B: stage 32KB quarter once (linear dest; ws already permuted) ------
  const bf16_t* wsQ = Wb + (size_t)(lin & 3) * 16384;
  bf16_t* lB = (bf16_t*)smem;
#pragma unroll
  for (int i = 0; i < 8; ++i) {
    const int c = tid + i * 256;
    async16(wsQ + c * 8, lB + c * 8);  // dest = wave-uniform + lane*16 OK
  }

  // --- A: issue the wave's ENTIRE K-slice (32 x f32x4) --------------------
  const float* pA[2];
#pragma unroll
  for (int mi = 0; mi < 2; ++mi) {
    int rr = row0 + wave * 32 + mi * 16 + l15;
    if (rr >= M) rr = M - 1;
    pA[mi] = A + (size_t)rr * HDIM + quad * 8;
  }
  f32x4 ar[8][2][2];  // [kstep][mi][half-of-8-floats]
#pragma unroll
  for (int ks = 0; ks < 8; ++ks)
#pragma unroll
    for (int mi = 0; mi < 2; ++mi) {
      ar[ks][mi][0] = *(const f32x4*)(pA[mi] + ks * 32);
      ar[ks][mi][1] = *(const f32x4*)(pA[mi] + ks * 32 + 4);
    }

  f32x4 acc[2][4];
#pragma unroll
  for (int mi = 0; mi < 2; ++mi)
#pragma unroll
    for (int ni = 0; ni < 4; ++ni) {
      f32x4 z = {0.f, 0.f, 0.f, 0.f};
      acc[mi][ni] = z;
    }

  __syncthreads();  // vmcnt(0) drain == the BW phase; B LDS + A regs ready

  // --- stall-free compute burst: no loads, no barriers --------------------
#pragma unroll
  for (int ks = 0; ks < 8; ++ks) {
    bf16x8 af[2];
#pragma unroll
    for (int mi = 0; mi < 2; ++mi) {
      f32x8 v = {ar[ks][mi][0][0], ar[ks][mi][0][1], ar[ks][mi][0][2],
                 ar[ks][mi][0][3], ar[ks][mi][1][0], ar[ks][mi][1][1],
                 ar[ks][mi][1][2], ar[ks][mi][1][3]};
      af[mi] = __builtin_convertvector(v, bf16x8);
    }
#pragma unroll
    for (int ni = 0; ni < 4; ++ni) {
      bf16x8 bfr = *(const bf16x8*)(smem + (ks * 4 + ni) * 1024 + lane * 16);
#pragma unroll
      for (int mi = 0; mi < 2; ++mi)
        acc[mi][ni] = __builtin_amdgcn_mfma_f32_16x16x32_bf16(
            af[mi], bfr, acc[mi][ni], 0, 0, 0);
    }
  }

  __syncthreads();  // all waves done reading B LDS -> staging may alias it

  // --- epilogue: C/D layout col = lane&15, row = quad*4 + reg --------------
  // Stage acc(+bias) into per-wave [16][68] f32, re-read coalesced:
  // lane map row = lane>>2, 4-col chunk = (lane&3)*4 + i*16 -> bf16x4 gathers
  // + dwordx4 stores. DS in-order within wave => no barrier inside.
  float bcol[4];
#pragma unroll
  for (int ni = 0; ni < 4; ++ni)
    bcol[ni] = bias[n0 + ni * 16 + l15];

  float* stage = (float*)smem + wave * (16 * 68);
  const int srow = lane >> 2;       // 0..15
  const int scol = (lane & 3) * 4;  // 0,4,8,12

#pragma unroll
  for (int mi = 0; mi < 2; ++mi) {
#pragma unroll
    for (int ni = 0; ni < 4; ++ni)
#pragma unroll
      for (int rg = 0; rg < 4; ++rg)
        stage[(quad * 4 + rg) * 68 + ni * 16 + l15] =
            acc[mi][ni][rg] + bcol[ni];

    const int row = row0 + wave * 32 + mi * 16 + srow;
    if (row < M) {
      const float* sp = stage + srow * 68;
      if constexpr (FUSED) {
        const int si = sIdxG[row];
        const int di = dIdxG[row];
        const bf16_t* vs = Vx + (size_t)si * HDIM + n0;
        const bf16_t* vd = Vx + (size_t)di * HDIM + n0;
        float* op = outF + (size_t)row * HDIM + n0;
#pragma unroll
        for (int i = 0; i < 4; ++i) {
          const int c = i * 16 + scol;
          f32x4 a = *(const f32x4*)(sp + c);
          f32x4 sf = __builtin_convertvector(*(const bf16x4*)(vs + c), f32x4);
          f32x4 df = __builtin_convertvector(*(const bf16x4*)(vd + c), f32x4);
          *(f32x4*)(op + c) = a + sf + df;
        }
      } else {
        bf16_t* op = outB + (size_t)row * HDIM + n0;
#pragma unroll
        for (int i = 0; i < 4; ++i) {
          const int c = i * 16 + scol;
          f32x4 a = *(const f32x4*)(sp + c);
          *(bf16x4*)(op + c) = __builtin_convertvector(a, bf16x4);
        }
      }
    }
  }
}

extern "C" void kernel_launch(void* const* d_in, const int* in_sizes, int n_in,
                              void* d_out, int out_size, void* d_ws,
                              size_t ws_size, hipStream_t stream) {
  const float* x = (const float*)d_in[0];     // (V, H) fp32
  const float* e = (const float*)d_in[1];     // (E, H) fp32
  const int* edge = (const int*)d_in[2];      // (2, E) int32: src then dst
  const float* Us_w = (const float*)d_in[3];  // (H, H) fp32
  const float* Us_b = (const float*)d_in[4];  // (H,) fp32
  const float* Vs_w = (const float*)d_in[5];  // (H, H) fp32
  const float* Vs_b = (const float*)d_in[6];  // (H,) fp32
  float* out = (float*)d_out;                 // (E, H) fp32

  bf16_t* us_w_b = (bf16_t*)d_ws;                         // 128 KB frag-order
  bf16_t* vs_w_b = (bf16_t*)((char*)d_ws + (128 << 10));  // 128 KB frag-order
  bf16_t* Vx = (bf16_t*)((char*)d_ws + (256 << 10));      // 5.12 MB

  dim3 blk(256, 1, 1);

  cvt_weights<<<dim3(32, 1, 1), blk, 0, stream>>>(Us_w, Vs_w, us_w_b, vs_w_b);

  const int n1 = 4 * ((NV + 127) / 128);  // 316
  gemm<false><<<dim3(n1, 1, 1), blk, 0, stream>>>(
      x, vs_w_b, Vs_b, nullptr, nullptr, nullptr, nullptr, Vx, NV);

  const int n2 = 4 * ((NE + 127) / 128);  // 9376
  gemm<true><<<dim3(n2, 1, 1), blk, 0, stream>>>(
      e, us_w_b, Us_b, edge, edge + NE, Vx, out, nullptr, NE);
}